// Round 13
// baseline (159.275 us; speedup 1.0000x reference)
//
#include <hip/hip_runtime.h>
#include <hip/hip_bf16.h>

typedef unsigned short u16;
typedef __attribute__((ext_vector_type(8))) short bf16x8;
typedef __attribute__((ext_vector_type(4))) float f32x4;
typedef __attribute__((ext_vector_type(8))) unsigned short u16x8;

#define GLDS(gp, lp) __builtin_amdgcn_global_load_lds( \
    (const __attribute__((address_space(1))) void*)(gp), \
    (__attribute__((address_space(3))) void*)(lp), 16, 0, 0)

__device__ __forceinline__ u16 f2b(float f) {
  unsigned u = __builtin_bit_cast(unsigned, f);
  return (u16)((u + 0x7fffu + ((u >> 16) & 1u)) >> 16);  // RNE, finite inputs
}
__device__ __forceinline__ float b2f(u16 s) {
  return __builtin_bit_cast(float, (unsigned)s << 16);
}

#define BARX() do { __builtin_amdgcn_sched_barrier(0); \
  asm volatile("s_barrier" ::: "memory"); \
  __builtin_amdgcn_sched_barrier(0); } while (0)

// ---------- kernel 0: f32 -> bf16 conversion (x, Wp|Wc|Ws packed, Wo) ----------
__global__ __launch_bounds__(256) void convert_k(
    const float* __restrict__ x, const float* __restrict__ Wp,
    const float* __restrict__ Wc, const float* __restrict__ Ws,
    const float* __restrict__ Wo, u16* __restrict__ xb,
    u16* __restrict__ wall, u16* __restrict__ wob)
{
  const long CX = 2097152;  // 16777216/8 x-chunks
  const long CW = 98304;    // 786432/8 packed-weight chunks
  const long CO = 32768;    // 262144/8 Wo chunks
  const long total = CX + CW + CO;
  for (long i = (long)blockIdx.x * blockDim.x + threadIdx.x; i < total;
       i += (long)gridDim.x * blockDim.x) {
    const float* src; u16* dst;
    if (i < CX) {
      src = x + i * 8; dst = xb + i * 8;
    } else if (i < CX + CW) {
      long e = (i - CX) * 8;
      int n = (int)(e >> 9), k = (int)(e & 511);
      const float* wr = (n < 512)  ? (Wp + (long)n * 512)
                      : (n < 1024) ? (Wc + (long)(n - 512) * 512)
                                   : (Ws + (long)(n - 1024) * 512);
      src = wr + k; dst = wall + e;
    } else {
      long e = (i - CX - CW) * 8; src = Wo + e; dst = wob + e;
    }
    f32x4 v0 = *(const f32x4*)src;
    f32x4 v1 = *(const f32x4*)(src + 4);
    u16x8 o;
    o[0]=f2b(v0[0]); o[1]=f2b(v0[1]); o[2]=f2b(v0[2]); o[3]=f2b(v0[3]);
    o[4]=f2b(v1[0]); o[5]=f2b(v1[1]); o[6]=f2b(v1[2]); o[7]=f2b(v1[3]);
    *(u16x8*)dst = o;
  }
}

// ---------- 256x256 GEMM, checkerboard wave phasing: C = A·Bw^T + bias ----------
// r7-verified skeleton (dbuf 128 KiB, whole-tile prefetch, ONE vmcnt(0)+barrier
// per tile, XOR-granule + XCD swizzles, LDS-staged epilogue). ONLY change:
// waves split into two groups g = wr ^ (wc&1) — opposite groups share a SIMD
// under either wave->SIMD mapping — and group 1 runs the tile's quadrants
// rotated by 2. At any instant half the waves feed LDS, half feed MFMA ->
// the two pipes overlap by construction instead of alternating in lockstep.
// Intra-tile order is correctness-free: reads hit buf p only, stages hit p^1.
template<int NC, bool BF16OUT>
__global__ __launch_bounds__(512, 2) void gemm8(
    const u16* __restrict__ A, const u16* __restrict__ Bw,
    const float* __restrict__ bias0, const float* __restrict__ bias1,
    const float* __restrict__ bias2, void* __restrict__ Cout)
{
  __shared__ alignas(16) char smem[131072];
  char* sAc = smem;            // [2][32768] A tiles: [256 rows][128 B]
  char* sBc = smem + 65536;    // [2][32768] B tiles

  const int tid = threadIdx.x;
  const int w = tid >> 6, lane = tid & 63;
  const int wr = w >> 2, wc = w & 3;          // 2 x 4 wave grid
  const int ln15 = lane & 15, g4 = lane >> 4, l7 = lane & 7;
  const int grp = wr ^ (wc & 1);              // checkerboard group

  // --- block swizzle: XCD-chunked (nwg % 8 == 0 for both instantiations) ---
  const int nbx = NC / 256;
  const int nwg = nbx * 128;
  const int qq = nwg / 8;
  const int flat = blockIdx.x;
  const int swz = (flat & 7) * qq + (flat >> 3);
  const int bx = swz % nbx, by = swz / nbx;
  const long row0 = (long)by * 256;
  const int col0 = bx * 256;

  // --- staging source pointers (inverse-swizzled global, linear LDS dest) ---
  const int gsw = (tid & 7) ^ ((tid >> 3) & 7);
  const u16* pA = A + (row0 + (tid >> 3)) * 512 + gsw * 8;
  const u16* pB = Bw + ((long)col0 + (tid >> 3)) * 512 + gsw * 8;

#define STAGE(pp, tt) do { \
    const u16* a0_ = pA + (tt) * 64; const u16* b0_ = pB + (tt) * 64; \
    char* da_ = sAc + (pp) * 32768 + w * 1024; \
    char* db_ = sBc + (pp) * 32768 + w * 1024; \
    GLDS(a0_, da_);          GLDS(a0_ + 32768, da_ + 8192); \
    GLDS(a0_ + 65536, da_ + 16384); GLDS(a0_ + 98304, da_ + 24576); \
    GLDS(b0_, db_);          GLDS(b0_ + 32768, db_ + 8192); \
    GLDS(b0_ + 65536, db_ + 16384); GLDS(b0_ + 98304, db_ + 24576); \
  } while (0)

  // --- fragment-read addressing (swizzled): row&7 == lane&7 for all frags ---
  const int gkb0 = ((0 + g4) ^ l7) * 16;   // kk=0 granule byte
  const int gkb1 = ((4 + g4) ^ l7) * 16;   // kk=1 granule byte
  const int arow = (wr * 128 + ln15) * 128;
  const int brow = (wc * 64 + ln15) * 128;

#define LOAD_A(MH) do { \
    _Pragma("unroll") for (int mf = 0; mf < 4; ++mf) { \
      aF[MH][mf][0] = *(const bf16x8*)(bufA + (MH) * 8192 + mf * 2048 + gkb0); \
      aF[MH][mf][1] = *(const bf16x8*)(bufA + (MH) * 8192 + mf * 2048 + gkb1); \
    } } while (0)
#define LOAD_B(NH) do { \
    _Pragma("unroll") for (int nf = 0; nf < 2; ++nf) { \
      bF[NH][nf][0] = *(const bf16x8*)(bufB + (NH) * 4096 + nf * 2048 + gkb0); \
      bF[NH][nf][1] = *(const bf16x8*)(bufB + (NH) * 4096 + nf * 2048 + gkb1); \
    } } while (0)
#define MFMA_Q(MH, NH) do { \
    __builtin_amdgcn_s_setprio(1); \
    _Pragma("unroll") for (int mf = 0; mf < 4; ++mf) \
    _Pragma("unroll") for (int nf = 0; nf < 2; ++nf) { \
      f32x4 c_ = acc[(MH) * 4 + mf][(NH) * 2 + nf]; \
      c_ = __builtin_amdgcn_mfma_f32_16x16x32_bf16(aF[MH][mf][0], bF[NH][nf][0], c_, 0, 0, 0); \
      c_ = __builtin_amdgcn_mfma_f32_16x16x32_bf16(aF[MH][mf][1], bF[NH][nf][1], c_, 0, 0, 0); \
      acc[(MH) * 4 + mf][(NH) * 2 + nf] = c_; \
    } \
    __builtin_amdgcn_s_setprio(0); \
  } while (0)

  f32x4 acc[8][4] = {};

  // prologue: stage K-tile 0 into buf 0
  STAGE(0, 0);
  asm volatile("s_waitcnt vmcnt(0)" ::: "memory");
  BARX();

  for (int t = 0; t < 8; ++t) {          // K = 512 / BK = 64
    const int p = t & 1;
    const char* bufA = sAc + p * 32768 + arow;
    const char* bufB = sBc + p * 32768 + brow;
    bf16x8 aF[2][4][2], bF[2][2][2];

    // prefetch next K-tile first: 8 GLDS stay in flight across the whole tile
    if (t < 7) STAGE(p ^ 1, t + 1);
    __builtin_amdgcn_sched_barrier(0);   // pin GLDS issue above the compute body

    // tile body: no barriers — reads hit buf p only, writes hit p^1 only.
    // Group 0 and group 1 run quadrants rotated by 2 -> anti-phased pipes.
    if (grp == 0) {
      LOAD_A(0); LOAD_B(0);
      MFMA_Q(0, 0);
      LOAD_B(1);
      MFMA_Q(0, 1);
      LOAD_A(1);
      MFMA_Q(1, 1);
      MFMA_Q(1, 0);
    } else {
      LOAD_A(1); LOAD_B(1);
      MFMA_Q(1, 1);
      LOAD_B(0);
      MFMA_Q(1, 0);
      LOAD_A(0);
      MFMA_Q(0, 0);
      MFMA_Q(0, 1);
    }

    if (t < 7) {
      asm volatile("s_waitcnt vmcnt(0)" ::: "memory");  // next tile fully staged
      BARX();                                           // buffer-swap barrier
    }
  }

  // ---- epilogue (r5-verified): per-wave LDS staging -> contiguous stores ----
  // acc[mi][n][j]: local row = mi*16 + g4*4 + j (0..127), local col = n*16 + ln15.
  __syncthreads();   // full drain; everyone done with sA/sB
  const long rgb = row0 + wr * 128;
  const int cgb = col0 + wc * 64;
  if (BF16OUT) {
    u16* sc = (u16*)(smem + (w << 14));      // 16 KiB/wave: [128][64] u16
#pragma unroll
    for (int n = 0; n < 4; ++n) {
      const int colg = cgb + ln15 + n * 16;
      const float* bp_ = (NC == 512) ? bias0
                         : (colg < 512 ? bias0 : (colg < 1024 ? bias1 : bias2));
      const float bv = bp_[colg & 511];
      const int c = ln15 + n * 16;
      const int gsl = c >> 3, co = c & 7;
#pragma unroll
      for (int mi = 0; mi < 8; ++mi)
#pragma unroll
        for (int j = 0; j < 4; ++j) {
          const int r = mi * 16 + (g4 << 2) + j;
          sc[r * 64 + (((gsl ^ (r & 7)) << 3) | co)] = f2b(acc[mi][n][j] + bv);
        }
    }
    asm volatile("s_waitcnt lgkmcnt(0)" ::: "memory");
    __builtin_amdgcn_sched_barrier(0);
#pragma unroll
    for (int it = 0; it < 16; ++it) {
      const int rr = it * 8 + (lane >> 3);
      const int gl = lane & 7;
      u16x8 v = *(const u16x8*)(sc + rr * 64 + ((gl ^ (rr & 7)) << 3));
      *(u16x8*)((u16*)Cout + (rgb + rr) * NC + cgb + gl * 8) = v;
    }
  } else {
    float* scf = (float*)(smem + (w << 14));  // 16 KiB/wave: [64][64] f32, 2 passes
#pragma unroll
    for (int h = 0; h < 2; ++h) {
#pragma unroll
      for (int n = 0; n < 4; ++n) {
        const int colg = cgb + ln15 + n * 16;
        const float bv = bias0[colg & 511];
        const int c = ln15 + n * 16;
        const int gsl = c >> 2, co = c & 3;
#pragma unroll
        for (int mf = 0; mf < 4; ++mf)
#pragma unroll
          for (int j = 0; j < 4; ++j) {
            const int r = mf * 16 + (g4 << 2) + j;
            scf[r * 64 + (((gsl ^ (r & 7)) << 2) | co)] = acc[h * 4 + mf][n][j] + bv;
          }
      }
      asm volatile("s_waitcnt lgkmcnt(0)" ::: "memory");
      __builtin_amdgcn_sched_barrier(0);
#pragma unroll
      for (int it = 0; it < 16; ++it) {
        const int rr = it * 4 + (lane >> 4);
        const int gl = lane & 15;
        f32x4 v = *(const f32x4*)(scf + rr * 64 + ((gl ^ (rr & 7)) << 2));
        *(f32x4*)((float*)Cout + (rgb + h * 64 + rr) * NC + cgb + gl * 4) = v;
      }
      asm volatile("s_waitcnt lgkmcnt(0)" ::: "memory");
      __builtin_amdgcn_sched_barrier(0);
    }
  }
#undef STAGE
#undef LOAD_A
#undef LOAD_B
#undef MFMA_Q
}

// ---------- attention: per-token 8x8 head-mix, one wave per token ----------
__global__ __launch_bounds__(256) void attn_k(const u16* __restrict__ PCS,
                                              u16* __restrict__ OUT)
{
  // per-wave f32 scratch: p[8][68], c[8][68], s[512], attn[64]  (pad 68 kills bank conflicts)
  __shared__ float L[4][1664];
  const int w = threadIdx.x >> 6, lane = threadIdx.x & 63;
  const long token = (long)blockIdx.x * 4 + w;
  float* Lw = L[w];
  const int C0 = 544, S0 = 1088, AT0 = 1600;
  const u16* rowp = PCS + token * 1536;
#pragma unroll
  for (int q = 0; q < 3; ++q) {
    u16x8 v = *(const u16x8*)(rowp + q * 512 + lane * 8);
    float* dst = (q < 2) ? (Lw + q * 544 + (lane >> 3) * 68 + (lane & 7) * 8)
                         : (Lw + S0 + lane * 8);
    f32x4 a = {b2f(v[0]), b2f(v[1]), b2f(v[2]), b2f(v[3])};
    f32x4 b = {b2f(v[4]), b2f(v[5]), b2f(v[6]), b2f(v[7])};
    *(f32x4*)dst = a;
    *(f32x4*)(dst + 4) = b;
  }
  // all data wave-local: no __syncthreads needed (wave-synchronous + in-order DS)
  const int h = lane >> 3, t = lane & 7;
  float sc = 0.f;
#pragma unroll
  for (int d = 0; d < 64; d += 4) {
    f32x4 pv = *(const f32x4*)(Lw + h * 68 + d);
    f32x4 cv = *(const f32x4*)(Lw + C0 + t * 68 + d);
    sc += pv[0]*cv[0] + pv[1]*cv[1] + pv[2]*cv[2] + pv[3]*cv[3];
  }
  sc *= 0.125f;  // 1/sqrt(D), D=64
  float mx = sc;
  mx = fmaxf(mx, __shfl_xor(mx, 1));
  mx = fmaxf(mx, __shfl_xor(mx, 2));
  mx = fmaxf(mx, __shfl_xor(mx, 4));
  float e = __expf(sc - mx);
  float sm = e;
  sm += __shfl_xor(sm, 1);
  sm += __shfl_xor(sm, 2);
  sm += __shfl_xor(sm, 4);
  Lw[AT0 + lane] = e / sm;
  float o[8] = {0, 0, 0, 0, 0, 0, 0, 0};
#pragma unroll
  for (int tt = 0; tt < 8; ++tt) {
    const float av = Lw[AT0 + h * 8 + tt];
    f32x4 s0 = *(const f32x4*)(Lw + S0 + tt * 64 + t * 8);
    f32x4 s1 = *(const f32x4*)(Lw + S0 + tt * 64 + t * 8 + 4);
    o[0] += av * s0[0]; o[1] += av * s0[1]; o[2] += av * s0[2]; o[3] += av * s0[3];
    o[4] += av * s1[0]; o[5] += av * s1[1]; o[6] += av * s1[2]; o[7] += av * s1[3];
  }
  u16x8 ov;
#pragma unroll
  for (int j = 0; j < 8; ++j) ov[j] = f2b(o[j]);
  // out element index within token = h*64 + (t*8+j) = lane*8+j -> coalesced 16B/lane
  *(u16x8*)(OUT + token * 512 + lane * 8) = ov;
}

extern "C" void kernel_launch(void* const* d_in, const int* in_sizes, int n_in,
                              void* d_out, int out_size, void* d_ws, size_t ws_size,
                              hipStream_t stream) {
  const float* x  = (const float*)d_in[0];
  const float* Wp = (const float*)d_in[1];
  const float* bp = (const float*)d_in[2];
  const float* Wc = (const float*)d_in[3];
  const float* bc = (const float*)d_in[4];
  const float* Ws = (const float*)d_in[5];
  const float* bs = (const float*)d_in[6];
  const float* Wo = (const float*)d_in[7];
  const float* bo = (const float*)d_in[8];

  char* ws = (char*)d_ws;
  u16* xb   = (u16*)ws;                      // 33,554,432 B  (x as bf16)
  u16* wall = (u16*)(ws + 33554432);         //  1,572,864 B  ([1536][512] Wp|Wc|Ws)
  u16* wob  = (u16*)(ws + 35127296);         //    524,288 B  ([512][512] Wo)
  u16* pcs  = (u16*)(ws + 35651584);         // 100,663,296 B ([32768][1536] p|c|s)
  u16* outb = xb;                            // overlay: xb dead after gemm1

  convert_k<<<2048, 256, 0, stream>>>(x, Wp, Wc, Ws, Wo, xb, wall, wob);
  gemm8<1536, true><<<768, 512, 0, stream>>>(xb, wall, bp, bc, bs, pcs);
  attn_k<<<8192, 256, 0, stream>>>(pcs, outb);
  gemm8<512, false><<<256, 512, 0, stream>>>(outb, wob, bo, bo, bo, d_out);
}

// Round 14
// 136.023 us; speedup vs baseline: 1.1709x; 1.1709x over previous
//
#include <hip/hip_runtime.h>
#include <hip/hip_bf16.h>

typedef unsigned short u16;
typedef __attribute__((ext_vector_type(8))) short bf16x8;
typedef __attribute__((ext_vector_type(4))) float f32x4;
typedef __attribute__((ext_vector_type(8))) unsigned short u16x8;

#define GLDS(gp, lp) __builtin_amdgcn_global_load_lds( \
    (const __attribute__((address_space(1))) void*)(gp), \
    (__attribute__((address_space(3))) void*)(lp), 16, 0, 0)

__device__ __forceinline__ u16 f2b(float f) {
  unsigned u = __builtin_bit_cast(unsigned, f);
  return (u16)((u + 0x7fffu + ((u >> 16) & 1u)) >> 16);  // RNE, finite inputs
}
__device__ __forceinline__ float b2f(u16 s) {
  return __builtin_bit_cast(float, (unsigned)s << 16);
}

#define BARX() do { __builtin_amdgcn_sched_barrier(0); \
  asm volatile("s_barrier" ::: "memory"); \
  __builtin_amdgcn_sched_barrier(0); } while (0)

// ---------- kernel 0: f32 -> bf16 conversion (x, Wp|Wc|Ws packed, Wo) ----------
__global__ __launch_bounds__(256) void convert_k(
    const float* __restrict__ x, const float* __restrict__ Wp,
    const float* __restrict__ Wc, const float* __restrict__ Ws,
    const float* __restrict__ Wo, u16* __restrict__ xb,
    u16* __restrict__ wall, u16* __restrict__ wob)
{
  const long CX = 2097152;  // 16777216/8 x-chunks
  const long CW = 98304;    // 786432/8 packed-weight chunks
  const long CO = 32768;    // 262144/8 Wo chunks
  const long total = CX + CW + CO;
  for (long i = (long)blockIdx.x * blockDim.x + threadIdx.x; i < total;
       i += (long)gridDim.x * blockDim.x) {
    const float* src; u16* dst;
    if (i < CX) {
      src = x + i * 8; dst = xb + i * 8;
    } else if (i < CX + CW) {
      long e = (i - CX) * 8;
      int n = (int)(e >> 9), k = (int)(e & 511);
      const float* wr = (n < 512)  ? (Wp + (long)n * 512)
                      : (n < 1024) ? (Wc + (long)(n - 512) * 512)
                                   : (Ws + (long)(n - 1024) * 512);
      src = wr + k; dst = wall + e;
    } else {
      long e = (i - CX - CW) * 8; src = Wo + e; dst = wob + e;
    }
    f32x4 v0 = *(const f32x4*)src;
    f32x4 v1 = *(const f32x4*)(src + 4);
    u16x8 o;
    o[0]=f2b(v0[0]); o[1]=f2b(v0[1]); o[2]=f2b(v0[2]); o[3]=f2b(v0[3]);
    o[4]=f2b(v1[0]); o[5]=f2b(v1[1]); o[6]=f2b(v1[2]); o[7]=f2b(v1[3]);
    *(u16x8*)dst = o;
  }
}

// ---------- 256x256 GEMM, single-buffer half-ping-pong (r10-verified) ----------
// A: [M][512] bf16, Bw: [NC][512] bf16. 512 threads = 8 waves (2M x 4N),
// per-wave 128x64, BK=64, LDS 64 KiB: [2 half][128 rows][128 B] per operand,
// consumption-aligned halves (A0,B0 die in ph1; B1 in ph2; A1 in ph3); stage
// into the region freed one phase earlier behind that phase's existing barrier.
// Counted vmcnt (steady 4/2/4; tail 4/2/0), 4 barriers/tile, XOR-granule swizzle
// both-sides, XCD-chunked block swizzle (skipped for NC=512: L3-resident).
template<int NC, bool BF16OUT>
__global__ __launch_bounds__(512, 2) void gemm8(
    const u16* __restrict__ A, const u16* __restrict__ Bw,
    const float* __restrict__ bias0, const float* __restrict__ bias1,
    const float* __restrict__ bias2, void* __restrict__ Cout)
{
  __shared__ alignas(16) char smem[65536];
  char* sAc = smem;            // [2 half][128 rows][128 B] consumption-aligned
  char* sBc = smem + 32768;

  const int tid = threadIdx.x;
  const int w = tid >> 6, lane = tid & 63;
  const int wr = w >> 2, wc = w & 3;          // 2 x 4 wave grid
  const int ln15 = lane & 15, g4 = lane >> 4, l7 = lane & 7;

  // --- block swizzle: XCD-chunked bijective for the big GEMM; identity for
  // NC=512 (working set L3-resident; m160: swizzle costs ~2% when L3-fit) ---
  const int nbx = NC / 256;
  int swz;
  if (NC == 512) {
    swz = blockIdx.x;
  } else {
    const int nwg = nbx * 128;
    const int qq = nwg / 8;
    const int flat = blockIdx.x;
    swz = (flat & 7) * qq + (flat >> 3);
  }
  const int bx = swz % nbx, by = swz / nbx;
  const long row0 = (long)by * 256;
  const int col0 = bx * 256;

  // --- staging source pointers (r10-verified) ---
  // A half h: local row lr -> global row row0 + (lr>>6)*128 + h*64 + (lr&63).
  // B half h: local row lr -> global row col0 + (lr>>5)*64 + h*32 + (lr&31).
  // slot s of local row lr holds global K-granule s ^ (lr&7).
  const int t8 = tid >> 3;
  const int gsw = (tid & 7) ^ (t8 & 7);
  const u16* pA = A + (row0 + t8) * 512 + gsw * 8;
  const u16* pB = Bw + ((long)col0 + (t8 >> 5) * 64 + (t8 & 31)) * 512 + gsw * 8;

#define STG_A(h, t) do { \
    const u16* s_ = pA + (h) * 32768 + (t) * 64; \
    char* d_ = sAc + (h) * 16384 + w * 1024; \
    GLDS(s_, d_); GLDS(s_ + 65536, d_ + 8192); \
  } while (0)
#define STG_B(h, t) do { \
    const u16* s_ = pB + (h) * 16384 + (t) * 64; \
    char* d_ = sBc + (h) * 16384 + w * 1024; \
    GLDS(s_, d_); GLDS(s_ + 65536, d_ + 8192); \
  } while (0)

  // --- fragment reads (swizzled): local row&7 == ln15&7 for all frags ---
  const int gkb0 = (g4 ^ l7) << 4;          // kk=0 swizzled granule byte
  const int gkb1 = ((g4 + 4) ^ l7) << 4;    // kk=1
  const int aoff = (wr * 64 + ln15) * 128;  // within A half
  const int boff = (wc * 32 + ln15) * 128;  // within B half

#define LOAD_A(MH) do { \
    const char* ba_ = sAc + (MH) * 16384 + aoff; \
    _Pragma("unroll") for (int mf = 0; mf < 4; ++mf) { \
      aF[mf][0] = *(const bf16x8*)(ba_ + mf * 2048 + gkb0); \
      aF[mf][1] = *(const bf16x8*)(ba_ + mf * 2048 + gkb1); \
    } } while (0)
#define LOAD_B(NH, BF) do { \
    const char* bb_ = sBc + (NH) * 16384 + boff; \
    _Pragma("unroll") for (int nf = 0; nf < 2; ++nf) { \
      BF[nf][0] = *(const bf16x8*)(bb_ + nf * 2048 + gkb0); \
      BF[nf][1] = *(const bf16x8*)(bb_ + nf * 2048 + gkb1); \
    } } while (0)
#define MFMA_Q(MH, NH, BF) do { \
    __builtin_amdgcn_s_setprio(1); \
    _Pragma("unroll") for (int mf = 0; mf < 4; ++mf) \
    _Pragma("unroll") for (int nf = 0; nf < 2; ++nf) { \
      f32x4 c_ = acc[(MH) * 4 + mf][(NH) * 2 + nf]; \
      c_ = __builtin_amdgcn_mfma_f32_16x16x32_bf16(aF[mf][0], BF[nf][0], c_, 0, 0, 0); \
      c_ = __builtin_amdgcn_mfma_f32_16x16x32_bf16(aF[mf][1], BF[nf][1], c_, 0, 0, 0); \
      acc[(MH) * 4 + mf][(NH) * 2 + nf] = c_; \
    } \
    __builtin_amdgcn_s_setprio(0); \
  } while (0)
#define VMW(nstr) asm volatile("s_waitcnt vmcnt(" nstr ")" ::: "memory")

  f32x4 acc[8][4] = {};

  // prologue: stage tile 0 in consumption order A0,B0,B1,A1 (8 GLDS)
  STG_A(0, 0); STG_B(0, 0); STG_B(1, 0); STG_A(1, 0);

  for (int t = 0; t < 8; ++t) {          // K = 512 / BK = 64
    const bool st = (t < 7);
    bf16x8 aF[4][2], bFa[2][2], bFb[2][2];

    // ph1: need A0,B0 (outstanding after them: B1,A1 = 4)
    VMW("4"); BARX();
    LOAD_A(0); LOAD_B(0, bFa);
    MFMA_Q(0, 0, bFa);
    // ph2: need B1 (outstanding after it: A1 = 2); A0,B0 regions freed -> stage
    VMW("2"); BARX();
    if (st) { STG_A(0, t + 1); STG_B(0, t + 1); }
    LOAD_B(1, bFb);
    MFMA_Q(0, 1, bFb);
    // ph3: need A1 (after it: A0B0[t+1] = 4 if staged, else 0); B1 freed -> stage
    if (st) VMW("4"); else VMW("0");
    BARX();
    if (st) STG_B(1, t + 1);
    LOAD_A(1);
    MFMA_Q(1, 1, bFb);
    // ph4: registers only; A1 freed -> stage
    BARX();
    if (st) STG_A(1, t + 1);
    MFMA_Q(1, 0, bFa);
  }

  // ---- epilogue: per-wave 8 KB LDS slices -> contiguous full-line stores ----
  // acc[mi][n][j]: local row = mi*16 + g4*4 + j (0..127), local col = n*16 + ln15.
  __syncthreads();   // all staging drained (vmcnt 0 since ph3 of t=7)
  const long rgb = row0 + wr * 128;
  const int cgb = col0 + wc * 64;
  if (BF16OUT) {
    u16* sc = (u16*)(smem + (w << 13));      // 8 KiB/wave: [64][64] u16
#pragma unroll
    for (int h2 = 0; h2 < 2; ++h2) {         // rows h2*64 .. h2*64+63
#pragma unroll
      for (int n = 0; n < 4; ++n) {
        const int colg = cgb + ln15 + n * 16;
        const float* bp_ = (NC == 512) ? bias0
                           : (colg < 512 ? bias0 : (colg < 1024 ? bias1 : bias2));
        const float bv = bp_[colg & 511];
        const int c = ln15 + n * 16;
        const int gsl = c >> 3, co = c & 7;
#pragma unroll
        for (int mf = 0; mf < 4; ++mf)
#pragma unroll
          for (int j = 0; j < 4; ++j) {
            const int r = mf * 16 + (g4 << 2) + j;   // 0..63 within slice
            sc[r * 64 + (((gsl ^ (r & 7)) << 3) | co)] = f2b(acc[h2 * 4 + mf][n][j] + bv);
          }
      }
      asm volatile("s_waitcnt lgkmcnt(0)" ::: "memory");
      __builtin_amdgcn_sched_barrier(0);
#pragma unroll
      for (int it = 0; it < 8; ++it) {
        const int rr = it * 8 + (lane >> 3);
        const int gl = lane & 7;
        u16x8 v = *(const u16x8*)(sc + rr * 64 + ((gl ^ (rr & 7)) << 3));
        *(u16x8*)((u16*)Cout + (rgb + h2 * 64 + rr) * NC + cgb + gl * 8) = v;
      }
      asm volatile("s_waitcnt lgkmcnt(0)" ::: "memory");
      __builtin_amdgcn_sched_barrier(0);
    }
  } else {
    float* scf = (float*)(smem + (w << 13));  // 8 KiB/wave: [32][64] f32, 4 passes
#pragma unroll
    for (int q = 0; q < 4; ++q) {             // rows q*32 .. q*32+31
#pragma unroll
      for (int n = 0; n < 4; ++n) {
        const int colg = cgb + ln15 + n * 16;
        const float bv = bias0[colg & 511];
        const int c = ln15 + n * 16;
        const int gsl = c >> 2, co = c & 3;
#pragma unroll
        for (int mh = 0; mh < 2; ++mh)
#pragma unroll
          for (int j = 0; j < 4; ++j) {
            const int r = mh * 16 + (g4 << 2) + j;  // 0..31 within slice
            scf[r * 64 + (((gsl ^ (r & 7)) << 2) | co)] = acc[q * 2 + mh][n][j] + bv;
          }
      }
      asm volatile("s_waitcnt lgkmcnt(0)" ::: "memory");
      __builtin_amdgcn_sched_barrier(0);
#pragma unroll
      for (int it = 0; it < 8; ++it) {
        const int rr = it * 4 + (lane >> 4);
        const int gl = lane & 15;
        f32x4 v = *(const f32x4*)(scf + rr * 64 + ((gl ^ (rr & 7)) << 2));
        *(f32x4*)((float*)Cout + (rgb + q * 32 + rr) * NC + cgb + gl * 4) = v;
      }
      asm volatile("s_waitcnt lgkmcnt(0)" ::: "memory");
      __builtin_amdgcn_sched_barrier(0);
    }
  }
#undef STG_A
#undef STG_B
#undef LOAD_A
#undef LOAD_B
#undef MFMA_Q
#undef VMW
}

// ---------- attention: per-token 8x8 head-mix, one wave per token ----------
__global__ __launch_bounds__(256) void attn_k(const u16* __restrict__ PCS,
                                              u16* __restrict__ OUT)
{
  // per-wave f32 scratch: p[8][68], c[8][68], s[512], attn[64]  (pad 68 kills bank conflicts)
  __shared__ float L[4][1664];
  const int w = threadIdx.x >> 6, lane = threadIdx.x & 63;
  const long token = (long)blockIdx.x * 4 + w;
  float* Lw = L[w];
  const int C0 = 544, S0 = 1088, AT0 = 1600;
  const u16* rowp = PCS + token * 1536;
#pragma unroll
  for (int q = 0; q < 3; ++q) {
    u16x8 v = *(const u16x8*)(rowp + q * 512 + lane * 8);
    float* dst = (q < 2) ? (Lw + q * 544 + (lane >> 3) * 68 + (lane & 7) * 8)
                         : (Lw + S0 + lane * 8);
    f32x4 a = {b2f(v[0]), b2f(v[1]), b2f(v[2]), b2f(v[3])};
    f32x4 b = {b2f(v[4]), b2f(v[5]), b2f(v[6]), b2f(v[7])};
    *(f32x4*)dst = a;
    *(f32x4*)(dst + 4) = b;
  }
  // all data wave-local: no __syncthreads needed (wave-synchronous + in-order DS)
  const int h = lane >> 3, t = lane & 7;
  float sc = 0.f;
#pragma unroll
  for (int d = 0; d < 64; d += 4) {
    f32x4 pv = *(const f32x4*)(Lw + h * 68 + d);
    f32x4 cv = *(const f32x4*)(Lw + C0 + t * 68 + d);
    sc += pv[0]*cv[0] + pv[1]*cv[1] + pv[2]*cv[2] + pv[3]*cv[3];
  }
  sc *= 0.125f;  // 1/sqrt(D), D=64
  float mx = sc;
  mx = fmaxf(mx, __shfl_xor(mx, 1));
  mx = fmaxf(mx, __shfl_xor(mx, 2));
  mx = fmaxf(mx, __shfl_xor(mx, 4));
  float e = __expf(sc - mx);
  float sm = e;
  sm += __shfl_xor(sm, 1);
  sm += __shfl_xor(sm, 2);
  sm += __shfl_xor(sm, 4);
  Lw[AT0 + lane] = e / sm;
  float o[8] = {0, 0, 0, 0, 0, 0, 0, 0};
#pragma unroll
  for (int tt = 0; tt < 8; ++tt) {
    const float av = Lw[AT0 + h * 8 + tt];
    f32x4 s0 = *(const f32x4*)(Lw + S0 + tt * 64 + t * 8);
    f32x4 s1 = *(const f32x4*)(Lw + S0 + tt * 64 + t * 8 + 4);
    o[0] += av * s0[0]; o[1] += av * s0[1]; o[2] += av * s0[2]; o[3] += av * s0[3];
    o[4] += av * s1[0]; o[5] += av * s1[1]; o[6] += av * s1[2]; o[7] += av * s1[3];
  }
  u16x8 ov;
#pragma unroll
  for (int j = 0; j < 8; ++j) ov[j] = f2b(o[j]);
  // out element index within token = h*64 + (t*8+j) = lane*8+j -> coalesced 16B/lane
  *(u16x8*)(OUT + token * 512 + lane * 8) = ov;
}

extern "C" void kernel_launch(void* const* d_in, const int* in_sizes, int n_in,
                              void* d_out, int out_size, void* d_ws, size_t ws_size,
                              hipStream_t stream) {
  const float* x  = (const float*)d_in[0];
  const float* Wp = (const float*)d_in[1];
  const float* bp = (const float*)d_in[2];
  const float* Wc = (const float*)d_in[3];
  const float* bc = (const float*)d_in[4];
  const float* Ws = (const float*)d_in[5];
  const float* bs = (const float*)d_in[6];
  const float* Wo = (const float*)d_in[7];
  const float* bo = (const float*)d_in[8];

  char* ws = (char*)d_ws;
  u16* xb   = (u16*)ws;                      // 33,554,432 B  (x as bf16)
  u16* wall = (u16*)(ws + 33554432);         //  1,572,864 B  ([1536][512] Wp|Wc|Ws)
  u16* wob  = (u16*)(ws + 35127296);         //    524,288 B  ([512][512] Wo)
  u16* pcs  = (u16*)(ws + 35651584);         // 100,663,296 B ([32768][1536] p|c|s)
  u16* outb = xb;                            // overlay: xb dead after gemm1

  convert_k<<<2048, 256, 0, stream>>>(x, Wp, Wc, Ws, Wo, xb, wall, wob);
  gemm8<1536, true><<<768, 512, 0, stream>>>(xb, wall, bp, bc, bs, pcs);
  attn_k<<<8192, 256, 0, stream>>>(pcs, outb);
  gemm8<512, false><<<256, 512, 0, stream>>>(outb, wob, bo, bo, bo, d_out);
}

// Round 15
// 132.380 us; speedup vs baseline: 1.2032x; 1.0275x over previous
//
#include <hip/hip_runtime.h>
#include <hip/hip_bf16.h>

typedef unsigned short u16;
typedef __attribute__((ext_vector_type(8))) short bf16x8;
typedef __attribute__((ext_vector_type(4))) float f32x4;
typedef __attribute__((ext_vector_type(8))) unsigned short u16x8;

#define GLDS(gp, lp) __builtin_amdgcn_global_load_lds( \
    (const __attribute__((address_space(1))) void*)(gp), \
    (__attribute__((address_space(3))) void*)(lp), 16, 0, 0)

__device__ __forceinline__ u16 f2b(float f) {
  unsigned u = __builtin_bit_cast(unsigned, f);
  return (u16)((u + 0x7fffu + ((u >> 16) & 1u)) >> 16);  // RNE, finite inputs
}
__device__ __forceinline__ float b2f(u16 s) {
  return __builtin_bit_cast(float, (unsigned)s << 16);
}

#define BARX() do { __builtin_amdgcn_sched_barrier(0); \
  asm volatile("s_barrier" ::: "memory"); \
  __builtin_amdgcn_sched_barrier(0); } while (0)

// ---------- kernel 0: f32 -> bf16 conversion (x, Wp|Wc|Ws packed, Wo) ----------
__global__ __launch_bounds__(256) void convert_k(
    const float* __restrict__ x, const float* __restrict__ Wp,
    const float* __restrict__ Wc, const float* __restrict__ Ws,
    const float* __restrict__ Wo, u16* __restrict__ xb,
    u16* __restrict__ wall, u16* __restrict__ wob)
{
  const long CX = 2097152;  // 16777216/8 x-chunks
  const long CW = 98304;    // 786432/8 packed-weight chunks
  const long CO = 32768;    // 262144/8 Wo chunks
  const long total = CX + CW + CO;
  for (long i = (long)blockIdx.x * blockDim.x + threadIdx.x; i < total;
       i += (long)gridDim.x * blockDim.x) {
    const float* src; u16* dst;
    if (i < CX) {
      src = x + i * 8; dst = xb + i * 8;
    } else if (i < CX + CW) {
      long e = (i - CX) * 8;
      int n = (int)(e >> 9), k = (int)(e & 511);
      const float* wr = (n < 512)  ? (Wp + (long)n * 512)
                      : (n < 1024) ? (Wc + (long)(n - 512) * 512)
                                   : (Ws + (long)(n - 1024) * 512);
      src = wr + k; dst = wall + e;
    } else {
      long e = (i - CX - CW) * 8; src = Wo + e; dst = wob + e;
    }
    f32x4 v0 = *(const f32x4*)src;
    f32x4 v1 = *(const f32x4*)(src + 4);
    u16x8 o;
    o[0]=f2b(v0[0]); o[1]=f2b(v0[1]); o[2]=f2b(v0[2]); o[3]=f2b(v0[3]);
    o[4]=f2b(v1[0]); o[5]=f2b(v1[1]); o[6]=f2b(v1[2]); o[7]=f2b(v1[3]);
    *(u16x8*)dst = o;
  }
}

// ---------- 256x256 GEMM, A staged 2 tiles ahead (triple-buffer), B 1 ahead ----------
// r10/r14-verified core. A: [M][512] bf16 (cold HBM -> needs >=900cyc flight),
// Bw: [NC][512] bf16 (L2-hot panel). 512 thr = 8 waves (2M x 4N), BK=64.
// LDS 128 KiB: A = 3 regions x [2 half][128 rows][128B] (region = t%3),
// B = [2 half][128 rows][128B] single-buffered per half.
// Issue order puts B0(t+1) BEFORE A0(t+2) so in-order vmcnt never forces an
// early A landing. Steady waits: ph1 vmcnt(6), ph2 vmcnt(2); tail t=7: 2/0.
// All flights >= ~2300 cyc vs 900 cyc HBM latency.
template<int NC, bool BF16OUT>
__global__ __launch_bounds__(512, 2) void gemm8(
    const u16* __restrict__ A, const u16* __restrict__ Bw,
    const float* __restrict__ bias0, const float* __restrict__ bias1,
    const float* __restrict__ bias2, void* __restrict__ Cout)
{
  __shared__ alignas(16) char smem[131072];
  char* sAc = smem;            // 3 x [2 half][128][128B] = 98304 B
  char* sBc = smem + 98304;    // [2 half][128][128B] = 32768 B

  const int tid = threadIdx.x;
  const int w = tid >> 6, lane = tid & 63;
  const int wr = w >> 2, wc = w & 3;          // 2 x 4 wave grid
  const int ln15 = lane & 15, g4 = lane >> 4, l7 = lane & 7;

  // --- block swizzle: XCD-chunked bijective (nwg % 8 == 0 for both) ---
  const int nbx = NC / 256;
  const int nwg = nbx * 128;
  const int qq = nwg / 8;
  const int flat = blockIdx.x;
  const int swz = (flat & 7) * qq + (flat >> 3);
  const int bx = swz % nbx, by = swz / nbx;
  const long row0 = (long)by * 256;
  const int col0 = bx * 256;

  // --- staging source pointers (r10-verified) ---
  // A half h: local row lr -> global row row0 + (lr>>6)*128 + h*64 + (lr&63).
  // B half h: local row lr -> global row col0 + (lr>>5)*64 + h*32 + (lr&31).
  // slot s of local row lr holds global K-granule s ^ (lr&7).
  const int t8 = tid >> 3;
  const int gsw = (tid & 7) ^ (t8 & 7);
  const u16* pA = A + (row0 + t8) * 512 + gsw * 8;
  const u16* pB = Bw + ((long)col0 + (t8 >> 5) * 64 + (t8 & 31)) * 512 + gsw * 8;

#define STG_A(h, tt) do { \
    const u16* s_ = pA + (h) * 32768 + (tt) * 64; \
    char* d_ = sAc + ((tt) % 3) * 32768 + (h) * 16384 + w * 1024; \
    GLDS(s_, d_); GLDS(s_ + 65536, d_ + 8192); \
  } while (0)
#define STG_B(h, tt) do { \
    const u16* s_ = pB + (h) * 16384 + (tt) * 64; \
    char* d_ = sBc + (h) * 16384 + w * 1024; \
    GLDS(s_, d_); GLDS(s_ + 65536, d_ + 8192); \
  } while (0)

  // --- fragment reads (swizzled): local row&7 == ln15&7 for all frags ---
  const int gkb0 = (g4 ^ l7) << 4;          // kk=0 swizzled granule byte
  const int gkb1 = ((g4 + 4) ^ l7) << 4;    // kk=1
  const int aoff = (wr * 64 + ln15) * 128;  // within A half
  const int boff = (wc * 32 + ln15) * 128;  // within B half

#define LOAD_A(MH) do { \
    const char* ba_ = bufA + (MH) * 16384 + aoff; \
    _Pragma("unroll") for (int mf = 0; mf < 4; ++mf) { \
      aF[mf][0] = *(const bf16x8*)(ba_ + mf * 2048 + gkb0); \
      aF[mf][1] = *(const bf16x8*)(ba_ + mf * 2048 + gkb1); \
    } } while (0)
#define LOAD_B(NH, BF) do { \
    const char* bb_ = sBc + (NH) * 16384 + boff; \
    _Pragma("unroll") for (int nf = 0; nf < 2; ++nf) { \
      BF[nf][0] = *(const bf16x8*)(bb_ + nf * 2048 + gkb0); \
      BF[nf][1] = *(const bf16x8*)(bb_ + nf * 2048 + gkb1); \
    } } while (0)
#define MFMA_Q(MH, NH, BF) do { \
    __builtin_amdgcn_s_setprio(1); \
    _Pragma("unroll") for (int mf = 0; mf < 4; ++mf) \
    _Pragma("unroll") for (int nf = 0; nf < 2; ++nf) { \
      f32x4 c_ = acc[(MH) * 4 + mf][(NH) * 2 + nf]; \
      c_ = __builtin_amdgcn_mfma_f32_16x16x32_bf16(aF[mf][0], BF[nf][0], c_, 0, 0, 0); \
      c_ = __builtin_amdgcn_mfma_f32_16x16x32_bf16(aF[mf][1], BF[nf][1], c_, 0, 0, 0); \
      acc[(MH) * 4 + mf][(NH) * 2 + nf] = c_; \
    } \
    __builtin_amdgcn_s_setprio(0); \
  } while (0)
#define VMW(nstr) asm volatile("s_waitcnt vmcnt(" nstr ")" ::: "memory")

  f32x4 acc[8][4] = {};

  // prologue: A(0), A(1) two tiles deep; B(0). Order chosen so the steady
  // in-order vmcnt pattern (ph1=6, ph2=2) holds from t=0.
  STG_A(0, 0); STG_A(1, 0); STG_B(0, 0); STG_A(0, 1); STG_B(1, 0); STG_A(1, 1);

  for (int t = 0; t < 8; ++t) {          // K = 512 / BK = 64
    const bool stB = (t < 7);            // stage B(t+1)
    const bool stA = (t < 6);            // stage A(t+2)
    const char* bufA = sAc + (t % 3) * 32768;
    bf16x8 aF[4][2], bFa[2][2], bFb[2][2];

    // ph1: need A0(t) [flight >=1 tile], B0(t) [flight 3 phases, L2-hot];
    // vmcnt(6) also drains A1(t) (older) -> whole tile's A is published here.
    if (t < 7) { VMW("6"); } else { VMW("2"); }
    BARX();
    LOAD_A(0); LOAD_B(0, bFa);
    MFMA_Q(0, 0, bFa);
    // ph2: need B1(t); drains A0(t+1) too (flight >=1 tile, harmless).
    if (t < 7) { VMW("2"); } else { VMW("0"); }
    BARX();
    if (stB) STG_B(0, t + 1);            // B BEFORE A: in-order counter
    if (stA) STG_A(0, t + 2);            //   never forces early A landing
    LOAD_B(1, bFb);
    MFMA_Q(0, 1, bFb);
    // ph3: A1(t) already landed (ph1's wait) and published (ph1's barrier).
    BARX();                              // WAR: B1 readers done before restage
    if (stB) STG_B(1, t + 1);
    LOAD_A(1);
    MFMA_Q(1, 1, bFb);
    // ph4: registers only.
    BARX();                              // WAR separation for A1 restage
    if (stA) STG_A(1, t + 2);
    MFMA_Q(1, 0, bFa);
  }

  // ---- epilogue: per-wave 8 KB LDS slices -> contiguous full-line stores ----
  // acc[mi][n][j]: local row = mi*16 + g4*4 + j (0..127), local col = n*16 + ln15.
  __syncthreads();   // vmcnt already 0 (t=7 ph2); full drain for LDS reuse
  const long rgb = row0 + wr * 128;
  const int cgb = col0 + wc * 64;
  if (BF16OUT) {
    u16* sc = (u16*)(smem + (w << 13));      // 8 KiB/wave: [64][64] u16
#pragma unroll
    for (int h2 = 0; h2 < 2; ++h2) {         // rows h2*64 .. h2*64+63
#pragma unroll
      for (int n = 0; n < 4; ++n) {
        const int colg = cgb + ln15 + n * 16;
        const float* bp_ = (NC == 512) ? bias0
                           : (colg < 512 ? bias0 : (colg < 1024 ? bias1 : bias2));
        const float bv = bp_[colg & 511];
        const int c = ln15 + n * 16;
        const int gsl = c >> 3, co = c & 7;
#pragma unroll
        for (int mf = 0; mf < 4; ++mf)
#pragma unroll
          for (int j = 0; j < 4; ++j) {
            const int r = mf * 16 + (g4 << 2) + j;   // 0..63 within slice
            sc[r * 64 + (((gsl ^ (r & 7)) << 3) | co)] = f2b(acc[h2 * 4 + mf][n][j] + bv);
          }
      }
      asm volatile("s_waitcnt lgkmcnt(0)" ::: "memory");
      __builtin_amdgcn_sched_barrier(0);
#pragma unroll
      for (int it = 0; it < 8; ++it) {
        const int rr = it * 8 + (lane >> 3);
        const int gl = lane & 7;
        u16x8 v = *(const u16x8*)(sc + rr * 64 + ((gl ^ (rr & 7)) << 3));
        *(u16x8*)((u16*)Cout + (rgb + h2 * 64 + rr) * NC + cgb + gl * 8) = v;
      }
      asm volatile("s_waitcnt lgkmcnt(0)" ::: "memory");
      __builtin_amdgcn_sched_barrier(0);
    }
  } else {
    float* scf = (float*)(smem + (w << 13));  // 8 KiB/wave: [32][64] f32, 4 passes
#pragma unroll
    for (int q = 0; q < 4; ++q) {             // rows q*32 .. q*32+31
#pragma unroll
      for (int n = 0; n < 4; ++n) {
        const int colg = cgb + ln15 + n * 16;
        const float bv = bias0[colg & 511];
        const int c = ln15 + n * 16;
        const int gsl = c >> 2, co = c & 3;
#pragma unroll
        for (int mh = 0; mh < 2; ++mh)
#pragma unroll
          for (int j = 0; j < 4; ++j) {
            const int r = mh * 16 + (g4 << 2) + j;  // 0..31 within slice
            scf[r * 64 + (((gsl ^ (r & 7)) << 2) | co)] = acc[q * 2 + mh][n][j] + bv;
          }
      }
      asm volatile("s_waitcnt lgkmcnt(0)" ::: "memory");
      __builtin_amdgcn_sched_barrier(0);
#pragma unroll
      for (int it = 0; it < 8; ++it) {
        const int rr = it * 4 + (lane >> 4);
        const int gl = lane & 15;
        f32x4 v = *(const f32x4*)(scf + rr * 64 + ((gl ^ (rr & 7)) << 2));
        *(f32x4*)((float*)Cout + (rgb + q * 32 + rr) * NC + cgb + gl * 4) = v;
      }
      asm volatile("s_waitcnt lgkmcnt(0)" ::: "memory");
      __builtin_amdgcn_sched_barrier(0);
    }
  }
#undef STG_A
#undef STG_B
#undef LOAD_A
#undef LOAD_B
#undef MFMA_Q
#undef VMW
}

// ---------- attention: per-token 8x8 head-mix, one wave per token ----------
__global__ __launch_bounds__(256) void attn_k(const u16* __restrict__ PCS,
                                              u16* __restrict__ OUT)
{
  // per-wave f32 scratch: p[8][68], c[8][68], s[512], attn[64]  (pad 68 kills bank conflicts)
  __shared__ float L[4][1664];
  const int w = threadIdx.x >> 6, lane = threadIdx.x & 63;
  const long token = (long)blockIdx.x * 4 + w;
  float* Lw = L[w];
  const int C0 = 544, S0 = 1088, AT0 = 1600;
  const u16* rowp = PCS + token * 1536;
#pragma unroll
  for (int q = 0; q < 3; ++q) {
    u16x8 v = *(const u16x8*)(rowp + q * 512 + lane * 8);
    float* dst = (q < 2) ? (Lw + q * 544 + (lane >> 3) * 68 + (lane & 7) * 8)
                         : (Lw + S0 + lane * 8);
    f32x4 a = {b2f(v[0]), b2f(v[1]), b2f(v[2]), b2f(v[3])};
    f32x4 b = {b2f(v[4]), b2f(v[5]), b2f(v[6]), b2f(v[7])};
    *(f32x4*)dst = a;
    *(f32x4*)(dst + 4) = b;
  }
  // all data wave-local: no __syncthreads needed (wave-synchronous + in-order DS)
  const int h = lane >> 3, t = lane & 7;
  float sc = 0.f;
#pragma unroll
  for (int d = 0; d < 64; d += 4) {
    f32x4 pv = *(const f32x4*)(Lw + h * 68 + d);
    f32x4 cv = *(const f32x4*)(Lw + C0 + t * 68 + d);
    sc += pv[0]*cv[0] + pv[1]*cv[1] + pv[2]*cv[2] + pv[3]*cv[3];
  }
  sc *= 0.125f;  // 1/sqrt(D), D=64
  float mx = sc;
  mx = fmaxf(mx, __shfl_xor(mx, 1));
  mx = fmaxf(mx, __shfl_xor(mx, 2));
  mx = fmaxf(mx, __shfl_xor(mx, 4));
  float e = __expf(sc - mx);
  float sm = e;
  sm += __shfl_xor(sm, 1);
  sm += __shfl_xor(sm, 2);
  sm += __shfl_xor(sm, 4);
  Lw[AT0 + lane] = e / sm;
  float o[8] = {0, 0, 0, 0, 0, 0, 0, 0};
#pragma unroll
  for (int tt = 0; tt < 8; ++tt) {
    const float av = Lw[AT0 + h * 8 + tt];
    f32x4 s0 = *(const f32x4*)(Lw + S0 + tt * 64 + t * 8);
    f32x4 s1 = *(const f32x4*)(Lw + S0 + tt * 64 + t * 8 + 4);
    o[0] += av * s0[0]; o[1] += av * s0[1]; o[2] += av * s0[2]; o[3] += av * s0[3];
    o[4] += av * s1[0]; o[5] += av * s1[1]; o[6] += av * s1[2]; o[7] += av * s1[3];
  }
  u16x8 ov;
#pragma unroll
  for (int j = 0; j < 8; ++j) ov[j] = f2b(o[j]);
  // out element index within token = h*64 + (t*8+j) = lane*8+j -> coalesced 16B/lane
  *(u16x8*)(OUT + token * 512 + lane * 8) = ov;
}

extern "C" void kernel_launch(void* const* d_in, const int* in_sizes, int n_in,
                              void* d_out, int out_size, void* d_ws, size_t ws_size,
                              hipStream_t stream) {
  const float* x  = (const float*)d_in[0];
  const float* Wp = (const float*)d_in[1];
  const float* bp = (const float*)d_in[2];
  const float* Wc = (const float*)d_in[3];
  const float* bc = (const float*)d_in[4];
  const float* Ws = (const float*)d_in[5];
  const float* bs = (const float*)d_in[6];
  const float* Wo = (const float*)d_in[7];
  const float* bo = (const float*)d_in[8];

  char* ws = (char*)d_ws;
  u16* xb   = (u16*)ws;                      // 33,554,432 B  (x as bf16)
  u16* wall = (u16*)(ws + 33554432);         //  1,572,864 B  ([1536][512] Wp|Wc|Ws)
  u16* wob  = (u16*)(ws + 35127296);         //    524,288 B  ([512][512] Wo)
  u16* pcs  = (u16*)(ws + 35651584);         // 100,663,296 B ([32768][1536] p|c|s)
  u16* outb = xb;                            // overlay: xb dead after gemm1

  convert_k<<<2048, 256, 0, stream>>>(x, Wp, Wc, Ws, Wo, xb, wall, wob);
  gemm8<1536, true><<<768, 512, 0, stream>>>(xb, wall, bp, bc, bs, pcs);
  attn_k<<<8192, 256, 0, stream>>>(pcs, outb);
  gemm8<512, false><<<256, 512, 0, stream>>>(outb, wob, bo, bo, bo, d_out);
}